// Round 1
// baseline (20603.055 us; speedup 1.0000x reference)
//
#include <hip/hip_runtime.h>
#include <cfloat>

// SequenceDecoder: 99 sequential GRU decode steps, B=128, EMB=512, H=1024, V=8192, T=100.
// Round 1: correct fp32 baseline.
//   - generic 128xN GEMM (A[128,K] @ W[N,K]^T + bias), 128x32 tile, 256 thr = 4 waves,
//     waves split each staged K-chunk (KC=64) 16 kk each, 8x8 microtile, LDS cross-wave reduce.
//   - classifier GEMM writes raw logits straight into out[:,t,:]; log_softmax normalization
//     deferred to a single final pass (argmax is shift-invariant).
//   - rowstats kernel: per-row max + first-occurrence argmax + logsumexp.

#define B_   128
#define EMB_ 512
#define H_   1024
#define V_   8192
#define T_   100
#define G3_  3072

#define AST 132   // As row stride (128 + 4 pad)
#define WST 36    // Ws row stride (32 + 4 pad)

__global__ __launch_bounds__(256) void gemm128(
    const float* __restrict__ A, int lda, const int* __restrict__ rowidx,
    const float* __restrict__ W, int ldw, const float* __restrict__ bias,
    float* __restrict__ C, long ldc, int K)
{
    __shared__ float As[64][AST];   // [kk][b], transposed
    __shared__ float Wsm[64][WST];  // [kk][j], transposed

    const int tid  = threadIdx.x;
    const int wv   = tid >> 6;        // wave 0..3
    const int lane = tid & 63;
    const int tb   = lane & 15;       // 16 b-groups
    const int tj   = lane >> 4;       // 4 j-groups
    const int b0   = tb << 3;         // 8 rows per thread
    const int j0t  = tj << 3;         // 8 cols per thread
    const int jb   = blockIdx.x << 5; // 32-wide j tile

    float acc[8][8] = {};

    const int nch = K >> 6;
    for (int ch = 0; ch < nch; ++ch) {
        const int k0 = ch << 6;
        __syncthreads();
        // stage A: 128 rows x 64 k  (2048 float4, 8 per thread)
        #pragma unroll
        for (int i = 0; i < 8; ++i) {
            const int id  = tid + (i << 8);
            const int row = id >> 4;
            const int kq  = id & 15;
            const int ar  = rowidx ? rowidx[row] : row;
            const float4 v = *(const float4*)(A + (size_t)ar * lda + k0 + (kq << 2));
            As[(kq << 2) + 0][row] = v.x;
            As[(kq << 2) + 1][row] = v.y;
            As[(kq << 2) + 2][row] = v.z;
            As[(kq << 2) + 3][row] = v.w;
        }
        // stage W: 32 rows x 64 k  (512 float4, 2 per thread)
        #pragma unroll
        for (int i = 0; i < 2; ++i) {
            const int id  = tid + (i << 8);
            const int row = id >> 4;
            const int kq  = id & 15;
            const float4 v = *(const float4*)(W + (size_t)(jb + row) * ldw + k0 + (kq << 2));
            Wsm[(kq << 2) + 0][row] = v.x;
            Wsm[(kq << 2) + 1][row] = v.y;
            Wsm[(kq << 2) + 2][row] = v.z;
            Wsm[(kq << 2) + 3][row] = v.w;
        }
        __syncthreads();
        // each wave consumes its 16-kk slice of the chunk
        #pragma unroll
        for (int kk = 0; kk < 16; ++kk) {
            const int kx = (wv << 4) + kk;
            const float4 a0 = *(const float4*)&As[kx][b0];
            const float4 a1 = *(const float4*)&As[kx][b0 + 4];
            const float4 w0 = *(const float4*)&Wsm[kx][j0t];
            const float4 w1 = *(const float4*)&Wsm[kx][j0t + 4];
            const float av[8]  = {a0.x, a0.y, a0.z, a0.w, a1.x, a1.y, a1.z, a1.w};
            const float wv8[8] = {w0.x, w0.y, w0.z, w0.w, w1.x, w1.y, w1.z, w1.w};
            #pragma unroll
            for (int ii = 0; ii < 8; ++ii)
                #pragma unroll
                for (int jj = 0; jj < 8; ++jj)
                    acc[ii][jj] = fmaf(av[ii], wv8[jj], acc[ii][jj]);
        }
    }

    // cross-wave reduce (waves hold disjoint K partials). reuse As as two 4224-float buffers.
    float* red = &As[0][0];
    float* r0  = red;
    float* r1  = red + 4224;
    __syncthreads();
    if (wv >= 2) {
        float* r = (wv == 2) ? r0 : r1;
        #pragma unroll
        for (int ii = 0; ii < 8; ++ii) {
            const int b = b0 + ii;
            #pragma unroll
            for (int jj = 0; jj < 8; ++jj) r[b * 33 + j0t + jj] = acc[ii][jj];
        }
    }
    __syncthreads();
    if (wv < 2) {
        float* r = (wv == 0) ? r0 : r1;
        #pragma unroll
        for (int ii = 0; ii < 8; ++ii) {
            const int b = b0 + ii;
            #pragma unroll
            for (int jj = 0; jj < 8; ++jj) acc[ii][jj] += r[b * 33 + j0t + jj];
        }
    }
    __syncthreads();
    if (wv == 1) {
        #pragma unroll
        for (int ii = 0; ii < 8; ++ii) {
            const int b = b0 + ii;
            #pragma unroll
            for (int jj = 0; jj < 8; ++jj) r0[b * 33 + j0t + jj] = acc[ii][jj];
        }
    }
    __syncthreads();
    if (wv == 0) {
        float bs[8];
        #pragma unroll
        for (int jj = 0; jj < 8; ++jj) bs[jj] = bias ? bias[jb + j0t + jj] : 0.f;
        #pragma unroll
        for (int ii = 0; ii < 8; ++ii) {
            const int b = b0 + ii;
            float v[8];
            #pragma unroll
            for (int jj = 0; jj < 8; ++jj)
                v[jj] = acc[ii][jj] + r0[b * 33 + j0t + jj] + bs[jj];
            float* cp = C + (size_t)b * ldc + jb + j0t;
            *(float4*)(cp)     = make_float4(v[0], v[1], v[2], v[3]);
            *(float4*)(cp + 4) = make_float4(v[4], v[5], v[6], v[7]);
        }
    }
}

__global__ void init_kernel(int* __restrict__ idx)
{
    if (threadIdx.x < B_) idx[threadIdx.x] = 0;  // argmax of start distribution = START_VALUE
}

__global__ void gates_kernel(const float* __restrict__ gi, const float* __restrict__ gh,
                             const float* __restrict__ hprev, float* __restrict__ hnew)
{
    const int i = blockIdx.x * 256 + threadIdx.x;  // 128*1024 total
    const int b = i >> 10;
    const int j = i & 1023;
    const int base = b * G3_;
    const float ir = gi[base + j];
    const float iz = gi[base + H_ + j];
    const float in_ = gi[base + 2 * H_ + j];
    const float hr = gh[base + j];
    const float hz = gh[base + H_ + j];
    const float hn = gh[base + 2 * H_ + j];
    const float r = 1.f / (1.f + __expf(0.f) * expf(-(ir + hr)));  // plain sigmoid
    const float z = 1.f / (1.f + expf(-(iz + hz)));
    const float n = tanhf(in_ + r * hn);
    hnew[i] = (1.f - z) * n + z * hprev[i];
}

__global__ void rowstats_kernel(const float* __restrict__ out, int t,
                                float* __restrict__ lse, int* __restrict__ idx)
{
    const int b = blockIdx.x;
    const float* row = out + (size_t)b * (T_ * (size_t)V_) + (size_t)t * V_;
    __shared__ float sm[256];
    __shared__ int   sa[256];
    const int tid = threadIdx.x;

    float m = -FLT_MAX;
    int   am = 0;
    for (int j = tid; j < V_; j += 256) {
        const float v = row[j];
        if (v > m) { m = v; am = j; }
    }
    sm[tid] = m; sa[tid] = am;
    __syncthreads();
    for (int s = 128; s > 0; s >>= 1) {
        if (tid < s) {
            const float m2 = sm[tid + s];
            const int   a2 = sa[tid + s];
            if (m2 > sm[tid] || (m2 == sm[tid] && a2 < sa[tid])) { sm[tid] = m2; sa[tid] = a2; }
        }
        __syncthreads();
    }
    const float M = sm[0];
    if (tid == 0) idx[b] = sa[0];
    __syncthreads();

    float s_ = 0.f;
    for (int j = tid; j < V_; j += 256) s_ += expf(row[j] - M);
    sm[tid] = s_;
    __syncthreads();
    for (int s = 128; s > 0; s >>= 1) {
        if (tid < s) sm[tid] += sm[tid + s];
        __syncthreads();
    }
    if (tid == 0) lse[b * T_ + t] = M + logf(sm[0]);
}

__global__ void finalize_kernel(float* __restrict__ out, const float* __restrict__ lse)
{
    // t==0 plane: log_softmax of one-hot at index 0; t>=1: subtract lse[b][t].
    const float lse0 = 1.0f + logf(1.0f + 8191.0f * expf(-1.0f));
    const unsigned total4 = (unsigned)(B_ * (size_t)T_ * V_ / 4);  // 26214400
    const unsigned stride = gridDim.x * blockDim.x;
    for (unsigned i = blockIdx.x * blockDim.x + threadIdx.x; i < total4; i += stride) {
        const unsigned lin = i * 4u;
        const unsigned b   = lin / (unsigned)(T_ * V_);
        const unsigned rem = lin - b * (unsigned)(T_ * V_);
        const unsigned t   = rem >> 13;      // /V_
        const unsigned j   = rem & (V_ - 1);
        float4* p = (float4*)out + i;
        float4 v;
        if (t == 0) {
            v.x = v.y = v.z = v.w = -lse0;
            if (j == 0) v.x = 1.0f - lse0;
        } else {
            const float l = lse[b * T_ + t];
            const float4 o = *p;
            v = make_float4(o.x - l, o.y - l, o.z - l, o.w - l);
        }
        *p = v;
    }
}

extern "C" void kernel_launch(void* const* d_in, const int* in_sizes, int n_in,
                              void* d_out, int out_size, void* d_ws, size_t ws_size,
                              hipStream_t stream)
{
    (void)in_sizes; (void)n_in; (void)out_size; (void)ws_size;
    const float* x     = (const float*)d_in[0];
    const float* emb   = (const float*)d_in[1];
    const float* w_ih  = (const float*)d_in[2];
    const float* w_hh  = (const float*)d_in[3];
    const float* b_ih  = (const float*)d_in[4];
    const float* b_hh  = (const float*)d_in[5];
    const float* cls_w = (const float*)d_in[6];
    const float* cls_b = (const float*)d_in[7];
    float* out = (float*)d_out;

    // workspace layout (floats): gi[128*3072] gh[128*3072] h0[128*1024] h1[128*1024] lse[128*100] idx[128]
    float* gi  = (float*)d_ws;
    float* gh  = gi + B_ * G3_;
    float* h0  = gh + B_ * G3_;
    float* h1  = h0 + B_ * H_;
    float* lse = h1 + B_ * H_;
    int*   idx = (int*)(lse + B_ * T_);

    init_kernel<<<dim3(1), dim3(128), 0, stream>>>(idx);

    const float* hprev = x;
    float* hbuf[2] = {h0, h1};
    for (int t = 1; t < T_; ++t) {
        // gi = emb[idx] @ w_ih^T + b_ih       (M=128, N=3072, K=512)
        gemm128<<<dim3(G3_ / 32), dim3(256), 0, stream>>>(emb, EMB_, idx, w_ih, EMB_, b_ih,
                                                          gi, (long)G3_, EMB_);
        // gh = hprev @ w_hh^T + b_hh          (M=128, N=3072, K=1024)
        gemm128<<<dim3(G3_ / 32), dim3(256), 0, stream>>>(hprev, H_, nullptr, w_hh, H_, b_hh,
                                                          gh, (long)G3_, H_);
        float* hnew = hbuf[(t - 1) & 1];
        gates_kernel<<<dim3(B_ * H_ / 256), dim3(256), 0, stream>>>(gi, gh, hprev, hnew);
        // logits -> out[:, t, :]              (M=128, N=8192, K=1024), raw (bias added, no lse yet)
        gemm128<<<dim3(V_ / 32), dim3(256), 0, stream>>>(hnew, H_, nullptr, cls_w, H_, cls_b,
                                                         out + (size_t)t * V_, (long)(T_ * (size_t)V_), H_);
        rowstats_kernel<<<dim3(B_), dim3(256), 0, stream>>>(out, t, lse, idx);
        hprev = hnew;
    }
    finalize_kernel<<<dim3(2048), dim3(256), 0, stream>>>(out, lse);
}

// Round 2
// 5871.653 us; speedup vs baseline: 3.5089x; 3.5089x over previous
//
#include <hip/hip_runtime.h>
#include <cfloat>

// SequenceDecoder: 99 sequential GRU decode steps, B=128, EMB=512, H=1024, V=8192, T=100.
// Round 2: fp16x2-split MFMA (32x32x16), zero-LDS GEMM with fragment-prearranged operands.
//   x = hi + lo*2^-12 (lo stored pre-scaled by 4096 to stay in fp16 normal range).
//   C = (ahi*bhi) + 2^-12*(ahi*blo + alo*bhi): 3 MFMAs, 2 fp32 accumulators -> ~fp32 accuracy.
//   A/B fragments packed by us with a self-consistent k-ordering (immune to k-grouping
//   ambiguity); C/D layout is the HW-verified m74/m101 mapping.

#define B_   128
#define EMB_ 512
#define H_   1024
#define V_   8192
#define T_   100
#define G3_  3072

typedef _Float16 half8 __attribute__((ext_vector_type(8)));
typedef float    f32x16 __attribute__((ext_vector_type(16)));

// ---------------- fragment packing helpers ----------------
// Element (m, k) of an M x K fp16 matrix lives at:
//   slot = ((m>>5)*(K/16) + (k>>4))*64 + (m&31) + 32*((k>>3)&1),  j = k&7  (8 halves per 16B slot)
// Same formula for weights with n in place of m (symmetric A/B packing).

__device__ __forceinline__ void split8(const float* __restrict__ src, half8& h, half8& l)
{
    const float4 v0 = *(const float4*)src;
    const float4 v1 = *(const float4*)(src + 4);
    const float xs[8] = {v0.x, v0.y, v0.z, v0.w, v1.x, v1.y, v1.z, v1.w};
    #pragma unroll
    for (int i = 0; i < 8; ++i) {
        const _Float16 hi = (_Float16)xs[i];
        h[i] = hi;
        l[i] = (_Float16)((xs[i] - (float)hi) * 4096.0f);
    }
}

// ---------------- one-time weight split ----------------
__global__ void wsplit_kernel(const float* __restrict__ W, half8* __restrict__ Wh,
                              half8* __restrict__ Wl, int N, int K)
{
    const int kpr = K >> 3;           // 16B slots per row
    const int nslots = N * kpr;
    for (int s = blockIdx.x * 256 + threadIdx.x; s < nslots; s += gridDim.x * 256) {
        const int n  = s / kpr;
        const int k8 = s - n * kpr;
        half8 h, l;
        split8(W + (size_t)n * K + k8 * 8, h, l);
        const int idx = ((n >> 5) * (K >> 4) + (k8 >> 1)) * 64 + (n & 31) + ((k8 & 1) << 5);
        Wh[idx] = h; Wl[idx] = l;
    }
}

// ---------------- init: h = x (fp32 + frags), e = emb[0] frags ----------------
__global__ void init_kernel(const float* __restrict__ x, const float* __restrict__ emb,
                            float* __restrict__ hf,
                            half8* __restrict__ Hh, half8* __restrict__ Hl,
                            half8* __restrict__ Eh, half8* __restrict__ El)
{
    const int gid = blockIdx.x * 256 + threadIdx.x;
    if (gid < B_ * (H_ / 8)) {                       // 16384: h slots
        const int b = gid >> 7, q = gid & 127;       // q: 8-elem group within row
        const float* src = x + (size_t)b * H_ + q * 8;
        *(float4*)(hf + (size_t)b * H_ + q * 8)     = *(const float4*)src;
        *(float4*)(hf + (size_t)b * H_ + q * 8 + 4) = *(const float4*)(src + 4);
        half8 h, l; split8(src, h, l);
        const int idx = ((b >> 5) * (H_ / 16) + (q >> 1)) * 64 + (b & 31) + ((q & 1) << 5);
        Hh[idx] = h; Hl[idx] = l;
    } else if (gid < B_ * (H_ / 8) + B_ * (EMB_ / 8)) {   // 8192: e slots (emb row 0)
        const int s = gid - B_ * (H_ / 8);
        const int b = s >> 6, q = s & 63;
        half8 h, l; split8(emb + q * 8, h, l);
        const int idx = ((b >> 5) * (EMB_ / 16) + (q >> 1)) * 64 + (b & 31) + ((q & 1) << 5);
        Eh[idx] = h; El[idx] = l;
    }
}

// ---------------- zero-LDS fp16x2 MFMA GEMM core ----------------
// Computes 64x64 block (rows mb*64.., cols n0..) over 32 ksteps (K=512 slice).
// 4 waves in 2x2; each wave one 32x32 tile via v_mfma_f32_32x32x16_f16.
__device__ __forceinline__ void gemm_core(
    const half8* __restrict__ Ah, const half8* __restrict__ Al, int AKs,
    const half8* __restrict__ Wh, const half8* __restrict__ Wl, int WKs,
    int ks0, int mb, int n0, float* __restrict__ C, int ldc)
{
    const int tid = threadIdx.x, w = tid >> 6, lane = tid & 63;
    const int wm = w >> 1, wn = w & 1;
    const int mt  = mb * 2 + wm;
    const int nfr = (n0 >> 5) + wn;
    const half8* ap_h = Ah + ((size_t)mt * AKs + ks0) * 64 + lane;
    const half8* ap_l = Al + ((size_t)mt * AKs + ks0) * 64 + lane;
    const half8* wp_h = Wh + ((size_t)nfr * WKs + ks0) * 64 + lane;
    const half8* wp_l = Wl + ((size_t)nfr * WKs + ks0) * 64 + lane;

    f32x16 accM = {};
    f32x16 accC = {};
    #pragma unroll 2
    for (int ks = 0; ks < 32; ++ks) {
        const half8 ah = ap_h[ks * 64];
        const half8 al = ap_l[ks * 64];
        const half8 wh = wp_h[ks * 64];
        const half8 wl = wp_l[ks * 64];
        accM = __builtin_amdgcn_mfma_f32_32x32x16_f16(ah, wh, accM, 0, 0, 0);
        accC = __builtin_amdgcn_mfma_f32_32x32x16_f16(ah, wl, accC, 0, 0, 0);
        accC = __builtin_amdgcn_mfma_f32_32x32x16_f16(al, wh, accC, 0, 0, 0);
    }
    // C/D layout (m74/m101): col = lane&31, row = (r&3) + 8*(r>>2) + 4*(lane>>5)
    const int col  = n0 + wn * 32 + (lane & 31);
    const int row0 = mb * 64 + wm * 32 + ((lane >> 5) << 2);
    #pragma unroll
    for (int r = 0; r < 16; ++r) {
        const int row = row0 + (r & 3) + ((r >> 2) << 3);
        C[(size_t)row * ldc + col] = accM[r] + accC[r] * (1.0f / 4096.0f);
    }
}

// Fused GRU GEMMs: jobs 0..95 = gi (E @ w_ih^T, K=512), 96..287 = gh halves (K=512 each).
__global__ __launch_bounds__(256, 2) void gru_gemm(
    const half8* __restrict__ Eh, const half8* __restrict__ El,
    const half8* __restrict__ Hh, const half8* __restrict__ Hl,
    const half8* __restrict__ WihH, const half8* __restrict__ WihL,
    const half8* __restrict__ WhhH, const half8* __restrict__ WhhL,
    float* __restrict__ gi, float* __restrict__ gh0, float* __restrict__ gh1)
{
    const int job = blockIdx.x;
    if (job >= 288) return;
    if (job < 96) {
        const int mb = job & 1, nt = job >> 1;
        gemm_core(Eh, El, EMB_ / 16, WihH, WihL, EMB_ / 16, 0, mb, nt * 64, gi, G3_);
    } else {
        const int j2 = job - 96;
        const int kp = j2 & 1, r2 = j2 >> 1;
        const int mb = r2 & 1, nt = r2 >> 1;
        gemm_core(Hh, Hl, H_ / 16, WhhH, WhhL, H_ / 16, kp * 32, mb, nt * 64,
                  kp ? gh1 : gh0, G3_);
    }
}

// Classifier: 512 blocks = 128 n-tiles x 2 m-blocks x 2 k-parts -> partials p0/p1.
__global__ __launch_bounds__(256, 2) void cls_gemm(
    const half8* __restrict__ Hh, const half8* __restrict__ Hl,
    const half8* __restrict__ WcH, const half8* __restrict__ WcL,
    float* __restrict__ p0, float* __restrict__ p1)
{
    const int b = blockIdx.x;
    const int kp = b & 1, r = b >> 1;
    const int mb = r & 1, nt = r >> 1;
    gemm_core(Hh, Hl, H_ / 16, WcH, WcL, H_ / 16, kp * 32, mb, nt * 64,
              kp ? p1 : p0, V_);
}

// ---------------- gates: h_new + h frags ----------------
__global__ void gates_kernel(const float* __restrict__ gi,
                             const float* __restrict__ g0, const float* __restrict__ g1,
                             const float* __restrict__ b_ih, const float* __restrict__ b_hh,
                             float* __restrict__ hf,
                             half8* __restrict__ Hh, half8* __restrict__ Hl)
{
    const int gid = blockIdx.x * 256 + threadIdx.x;   // 16384
    const int b = gid >> 7, q = gid & 127, j0 = q * 8;
    const size_t base = (size_t)b * G3_;
    float hn8[8];
    float hp[8];
    {
        const float4 h0 = *(const float4*)(hf + (size_t)b * H_ + j0);
        const float4 h1 = *(const float4*)(hf + (size_t)b * H_ + j0 + 4);
        hp[0]=h0.x; hp[1]=h0.y; hp[2]=h0.z; hp[3]=h0.w; hp[4]=h1.x; hp[5]=h1.y; hp[6]=h1.z; hp[7]=h1.w;
    }
    #pragma unroll
    for (int p = 0; p < 2; ++p) {       // two float4 groups
        const int j = j0 + p * 4;
        const float4 ir4 = *(const float4*)(gi + base + j);
        const float4 iz4 = *(const float4*)(gi + base + H_ + j);
        const float4 in4 = *(const float4*)(gi + base + 2 * H_ + j);
        const float4 hr4a = *(const float4*)(g0 + base + j);
        const float4 hz4a = *(const float4*)(g0 + base + H_ + j);
        const float4 hn4a = *(const float4*)(g0 + base + 2 * H_ + j);
        const float4 hr4b = *(const float4*)(g1 + base + j);
        const float4 hz4b = *(const float4*)(g1 + base + H_ + j);
        const float4 hn4b = *(const float4*)(g1 + base + 2 * H_ + j);
        const float4 bir = *(const float4*)(b_ih + j);
        const float4 biz = *(const float4*)(b_ih + H_ + j);
        const float4 bin = *(const float4*)(b_ih + 2 * H_ + j);
        const float4 bhr = *(const float4*)(b_hh + j);
        const float4 bhz = *(const float4*)(b_hh + H_ + j);
        const float4 bhn = *(const float4*)(b_hh + 2 * H_ + j);
        const float ir[4] = {ir4.x + bir.x, ir4.y + bir.y, ir4.z + bir.z, ir4.w + bir.w};
        const float iz[4] = {iz4.x + biz.x, iz4.y + biz.y, iz4.z + biz.z, iz4.w + biz.w};
        const float in_[4] = {in4.x + bin.x, in4.y + bin.y, in4.z + bin.z, in4.w + bin.w};
        const float hr[4] = {hr4a.x + hr4b.x + bhr.x, hr4a.y + hr4b.y + bhr.y,
                             hr4a.z + hr4b.z + bhr.z, hr4a.w + hr4b.w + bhr.w};
        const float hz[4] = {hz4a.x + hz4b.x + bhz.x, hz4a.y + hz4b.y + bhz.y,
                             hz4a.z + hz4b.z + bhz.z, hz4a.w + hz4b.w + bhz.w};
        const float hn[4] = {hn4a.x + hn4b.x + bhn.x, hn4a.y + hn4b.y + bhn.y,
                             hn4a.z + hn4b.z + bhn.z, hn4a.w + hn4b.w + bhn.w};
        #pragma unroll
        for (int i = 0; i < 4; ++i) {
            const float r = 1.0f / (1.0f + expf(-(ir[i] + hr[i])));
            const float z = 1.0f / (1.0f + expf(-(iz[i] + hz[i])));
            const float n = tanhf(in_[i] + r * hn[i]);
            hn8[p * 4 + i] = (1.0f - z) * n + z * hp[p * 4 + i];
        }
    }
    // write fp32 h (in place; each thread owns its 8 elements)
    *(float4*)(hf + (size_t)b * H_ + j0)     = make_float4(hn8[0], hn8[1], hn8[2], hn8[3]);
    *(float4*)(hf + (size_t)b * H_ + j0 + 4) = make_float4(hn8[4], hn8[5], hn8[6], hn8[7]);
    // frag write
    half8 h, l;
    #pragma unroll
    for (int i = 0; i < 8; ++i) {
        const _Float16 hi = (_Float16)hn8[i];
        h[i] = hi;
        l[i] = (_Float16)((hn8[i] - (float)hi) * 4096.0f);
    }
    const int idx = ((b >> 5) * (H_ / 16) + (q >> 1)) * 64 + (b & 31) + ((q & 1) << 5);
    Hh[idx] = h; Hl[idx] = l;
}

// ---------------- rowstats: reduce partials + bias -> out, max/argmax/lse, gather+split e ----------------
__global__ void rowstats_kernel(const float* __restrict__ P0, const float* __restrict__ P1,
                                const float* __restrict__ cls_b, float* __restrict__ out, int t,
                                float* __restrict__ lse, const float* __restrict__ emb,
                                half8* __restrict__ Eh, half8* __restrict__ El)
{
    const int b = blockIdx.x;
    const int tid = threadIdx.x;
    __shared__ float srow[V_];
    __shared__ float sm[256];
    __shared__ int   sa[256];
    const float* p0 = P0 + (size_t)b * V_;
    const float* p1 = P1 + (size_t)b * V_;
    float* orow = out + (size_t)b * (T_ * (size_t)V_) + (size_t)t * V_;

    float m = -FLT_MAX; int am = 0;
    for (int j = tid * 4; j < V_; j += 1024) {
        const float4 a = *(const float4*)(p0 + j);
        const float4 c = *(const float4*)(p1 + j);
        const float4 bb = *(const float4*)(cls_b + j);
        const float v[4] = {a.x + c.x + bb.x, a.y + c.y + bb.y, a.z + c.z + bb.z, a.w + c.w + bb.w};
        *(float4*)(srow + j) = make_float4(v[0], v[1], v[2], v[3]);
        *(float4*)(orow + j) = make_float4(v[0], v[1], v[2], v[3]);
        #pragma unroll
        for (int i = 0; i < 4; ++i)
            if (v[i] > m) { m = v[i]; am = j + i; }
    }
    sm[tid] = m; sa[tid] = am;
    __syncthreads();
    for (int s = 128; s > 0; s >>= 1) {
        if (tid < s) {
            const float m2 = sm[tid + s]; const int a2 = sa[tid + s];
            if (m2 > sm[tid] || (m2 == sm[tid] && a2 < sa[tid])) { sm[tid] = m2; sa[tid] = a2; }
        }
        __syncthreads();
    }
    const float M = sm[0];
    const int amax = sa[0];
    __syncthreads();

    float s_ = 0.0f;
    for (int j = tid * 4; j < V_; j += 1024) {
        const float4 v = *(const float4*)(srow + j);
        s_ += expf(v.x - M) + expf(v.y - M) + expf(v.z - M) + expf(v.w - M);
    }
    sm[tid] = s_;
    __syncthreads();
    for (int s = 128; s > 0; s >>= 1) {
        if (tid < s) sm[tid] += sm[tid + s];
        __syncthreads();
    }
    if (tid == 0) lse[b * T_ + t] = M + logf(sm[0]);

    // gather next-step embedding row and write its frags
    if (tid < EMB_ / 8) {
        const int q = tid;
        half8 h, l;
        split8(emb + (size_t)amax * EMB_ + q * 8, h, l);
        const int idx = ((b >> 5) * (EMB_ / 16) + (q >> 1)) * 64 + (b & 31) + ((q & 1) << 5);
        Eh[idx] = h; El[idx] = l;
    }
}

// ---------------- finalize: t=0 plane + subtract lse ----------------
__global__ void finalize_kernel(float* __restrict__ out, const float* __restrict__ lse)
{
    const float lse0 = 1.0f + logf(1.0f + 8191.0f * expf(-1.0f));
    const unsigned total4 = (unsigned)(B_ * (size_t)T_ * V_ / 4);
    const unsigned stride = gridDim.x * blockDim.x;
    for (unsigned i = blockIdx.x * blockDim.x + threadIdx.x; i < total4; i += stride) {
        const unsigned lin = i * 4u;
        const unsigned b   = lin / (unsigned)(T_ * V_);
        const unsigned rem = lin - b * (unsigned)(T_ * V_);
        const unsigned t   = rem >> 13;
        const unsigned j   = rem & (V_ - 1);
        float4* p = (float4*)out + i;
        float4 v;
        if (t == 0) {
            v.x = v.y = v.z = v.w = -lse0;
            if (j == 0) v.x = 1.0f - lse0;
        } else {
            const float l = lse[b * T_ + t];
            const float4 o = *p;
            v = make_float4(o.x - l, o.y - l, o.z - l, o.w - l);
        }
        *p = v;
    }
}

extern "C" void kernel_launch(void* const* d_in, const int* in_sizes, int n_in,
                              void* d_out, int out_size, void* d_ws, size_t ws_size,
                              hipStream_t stream)
{
    (void)in_sizes; (void)n_in; (void)out_size; (void)ws_size;
    const float* x     = (const float*)d_in[0];
    const float* emb   = (const float*)d_in[1];
    const float* w_ih  = (const float*)d_in[2];
    const float* w_hh  = (const float*)d_in[3];
    const float* b_ih  = (const float*)d_in[4];
    const float* b_hh  = (const float*)d_in[5];
    const float* cls_w = (const float*)d_in[6];
    const float* cls_b = (const float*)d_in[7];
    float* out = (float*)d_out;

    // workspace carve-up (256B aligned)
    char* p = (char*)d_ws;
    auto alloc = [&](size_t bytes) { void* r = p; p += (bytes + 255) & ~(size_t)255; return r; };
    half8* wihH = (half8*)alloc((size_t)G3_ * EMB_ * 2);
    half8* wihL = (half8*)alloc((size_t)G3_ * EMB_ * 2);
    half8* whhH = (half8*)alloc((size_t)G3_ * H_ * 2);
    half8* whhL = (half8*)alloc((size_t)G3_ * H_ * 2);
    half8* wcH  = (half8*)alloc((size_t)V_ * H_ * 2);
    half8* wcL  = (half8*)alloc((size_t)V_ * H_ * 2);
    half8* Eh   = (half8*)alloc((size_t)B_ * EMB_ * 2);
    half8* El   = (half8*)alloc((size_t)B_ * EMB_ * 2);
    half8* Hh   = (half8*)alloc((size_t)B_ * H_ * 2);
    half8* Hl   = (half8*)alloc((size_t)B_ * H_ * 2);
    float* hf   = (float*)alloc((size_t)B_ * H_ * 4);
    float* gi   = (float*)alloc((size_t)B_ * G3_ * 4);
    float* gh0  = (float*)alloc((size_t)B_ * G3_ * 4);
    float* gh1  = (float*)alloc((size_t)B_ * G3_ * 4);
    float* cp0  = (float*)alloc((size_t)B_ * V_ * 4);
    float* cp1  = (float*)alloc((size_t)B_ * V_ * 4);
    float* lse  = (float*)alloc((size_t)B_ * T_ * 4);

    // one-time (per launch) weight splits
    wsplit_kernel<<<dim3(1024), dim3(256), 0, stream>>>(w_ih, wihH, wihL, G3_, EMB_);
    wsplit_kernel<<<dim3(1024), dim3(256), 0, stream>>>(w_hh, whhH, whhL, G3_, H_);
    wsplit_kernel<<<dim3(2048), dim3(256), 0, stream>>>(cls_w, wcH, wcL, V_, H_);
    init_kernel<<<dim3(96), dim3(256), 0, stream>>>(x, emb, hf, Hh, Hl, Eh, El);

    for (int t = 1; t < T_; ++t) {
        gru_gemm<<<dim3(512), dim3(256), 0, stream>>>(Eh, El, Hh, Hl,
                                                      wihH, wihL, whhH, whhL, gi, gh0, gh1);
        gates_kernel<<<dim3(64), dim3(256), 0, stream>>>(gi, gh0, gh1, b_ih, b_hh, hf, Hh, Hl);
        cls_gemm<<<dim3(512), dim3(256), 0, stream>>>(Hh, Hl, wcH, wcL, cp0, cp1);
        rowstats_kernel<<<dim3(B_), dim3(256), 0, stream>>>(cp0, cp1, cls_b, out, t, lse, emb, Eh, El);
    }
    finalize_kernel<<<dim3(2048), dim3(256), 0, stream>>>(out, lse);
}